// Round 7
// baseline (1138.898 us; speedup 1.0000x reference)
//
#include <hip/hip_runtime.h>
#include <hip/hip_bf16.h>

#define NN 50000
#define NE 800000

typedef unsigned short u16;
typedef unsigned int u32;

__device__ __forceinline__ float bf2f(u16 u) {
    u32 x = ((u32)u) << 16;
    return __uint_as_float(x);
}
__device__ __forceinline__ u16 f2bf(float f) {
    u32 x = __float_as_uint(f);
    u32 r = (x + 0x7fffu + ((x >> 16) & 1u)) >> 16;  // round-nearest-even
    return (u16)r;
}
__device__ __forceinline__ u32 pack2(float a, float b) {
    return (u32)f2bf(a) | ((u32)f2bf(b) << 16);
}
__device__ __forceinline__ void unpack8(uint4 u, float* o) {
    o[0] = bf2f((u16)(u.x & 0xffff)); o[1] = bf2f((u16)(u.x >> 16));
    o[2] = bf2f((u16)(u.y & 0xffff)); o[3] = bf2f((u16)(u.y >> 16));
    o[4] = bf2f((u16)(u.z & 0xffff)); o[5] = bf2f((u16)(u.z >> 16));
    o[6] = bf2f((u16)(u.w & 0xffff)); o[7] = bf2f((u16)(u.w >> 16));
}
__device__ __forceinline__ float ldf(const void* p, size_t idx, int mode) {
    return mode ? bf2f(((const u16*)p)[idx]) : ((const float*)p)[idx];
}
__device__ __forceinline__ float lrelu(float x) { return x > 0.f ? x : 0.2f * x; }

// ---------------- diagnostics ----------------
__global__ void k_tracer(float* out, float v) {
    if (threadIdx.x == 0 && blockIdx.x == 0) out[0] = v;
}

// ---------------- dtype detect (0 = f32 inputs, 1 = bf16 inputs) ----------------
__global__ void k_detect(const u16* __restrict__ fvs, int* __restrict__ mode) {
    __shared__ int cnt[256];
    int t = threadIdx.x;
    int bad = 0;
    for (int i = 0; i < 16; i++) {
        u16 u = fvs[(size_t)(t * 16 + i) * 2];
        int e = (u >> 7) & 0xff;
        if (e == 255 || e >= 134 || e <= 100) bad++;
    }
    cnt[t] = bad;
    __syncthreads();
    for (int d = 128; d; d >>= 1) {
        if (t < d) cnt[t] += cnt[t + d];
        __syncthreads();
    }
    if (t == 0) *mode = (cnt[0] > 2048) ? 0 : 1;
}

// ---------------- CSR build ----------------
__global__ void k_hist(const int* __restrict__ dst, int* __restrict__ cnt, int E) {
    int e = blockIdx.x * blockDim.x + threadIdx.x;
    if (e < E) atomicAdd(&cnt[dst[e]], 1);
}

__global__ void k_scan(const int* __restrict__ cnt, int* __restrict__ off, int N) {
    __shared__ int sums[1024];
    int t = threadIdx.x;
    int chunk = (N + 1023) >> 10;
    int b = t * chunk;
    int s = 0;
    for (int i = 0; i < chunk; i++) { int idx = b + i; if (idx < N) s += cnt[idx]; }
    sums[t] = s;
    __syncthreads();
    for (int d = 1; d < 1024; d <<= 1) {
        int v = (t >= d) ? sums[t - d] : 0;
        __syncthreads();
        sums[t] += v;
        __syncthreads();
    }
    int run = (t == 0) ? 0 : sums[t - 1];
    for (int i = 0; i < chunk; i++) {
        int idx = b + i;
        if (idx < N) { off[idx] = run; run += cnt[idx]; }
    }
    if (t == 1023) off[N] = sums[1023];
}

__global__ void k_fill(const int* __restrict__ src, const int* __restrict__ dst,
                       const int* __restrict__ off, int* __restrict__ cnt2,
                       int* __restrict__ ssrc, int E) {
    int e = blockIdx.x * blockDim.x + threadIdx.x;
    if (e < E) {
        int d = dst[e];
        int p = off[d] + atomicAdd(&cnt2[d], 1);
        ssrc[p] = src[e];
    }
}

// ---------------- init: hp = bf16(pos) ----------------
__global__ void k_init(const void* __restrict__ pos, u16* __restrict__ hp,
                       const int* __restrict__ dmode, int n64) {
    int i = blockIdx.x * blockDim.x + threadIdx.x;
    if (i >= n64) return;
    int mode = *dmode;
    hp[i] = mode ? ((const u16*)pos)[i] : f2bf(((const float*)pos)[i]);
}

// ---------------- hp (bf16) -> f32 ----------------
__global__ void k_cvt(const u16* __restrict__ in, float* __restrict__ out, int n) {
    int i = blockIdx.x * blockDim.x + threadIdx.x;
    if (i < n) out[i] = bf2f(in[i]);
}

// ---------------- GEMM (BK=16) + fused el/er epilogue ----------------
// C1[N,BM](f32), C2[N,BM](bf16) = [A1|A2][N,K] x B1/B2[K,BM]
// BK=16 halves LDS (~21KB) for occupancy; register prefetch of next K-tile.
// A1 and C2 may alias (in-place): block touches only its own 64 rows.
template <int BM, bool HASB2>
__launch_bounds__(256, 4)
__global__ void k_gemm(const void* A1, const u16* __restrict__ A2,
                       const void* __restrict__ B1, const void* __restrict__ B2,
                       float* __restrict__ C1, u16* C2, float* __restrict__ att,
                       const void* __restrict__ al, const void* __restrict__ ar,
                       int N, int K, int s1, const int* __restrict__ dmode,
                       int a1_input) {
    constexpr int NG = BM / 32;      // col pair-groups per thread (4 or 2)
    constexpr int BPR = BM / 8;      // 8-float chunks per B row
    __shared__ alignas(16) float As[16][68];
    __shared__ alignas(16) float Bs1[16][BM + 4];
    __shared__ alignas(16) float Bs2[HASB2 ? 16 : 1][HASB2 ? BM + 4 : 1];

    int mode = *dmode;
    int amode = a1_input ? mode : 1;
    int tid = threadIdx.x;
    int tx = tid & 15, ty = tid >> 4;
    int r0 = blockIdx.x * 64;
    int arow = tid >> 2, col4 = (tid & 3) * 4;
    int gr_a = r0 + arow;

    bool bact = tid < 2 * BM;        // B staging: 2*BM chunks of 8 floats
    int brow = tid / BPR, bcol = (tid % BPR) * 8;

    uint4 pa; uint2 pa2; uint4 pb1[2], pb2[2];

    auto loadA = [&](int k0) {
        if (gr_a >= N) return;
        if (k0 >= 128) {
            pa2 = *(const uint2*)&A2[(size_t)gr_a * 64 + (k0 - 128) + col4];
        } else if (amode) {
            pa2 = *(const uint2*)((const u16*)A1 + (size_t)gr_a * s1 + k0 + col4);
        } else {
            pa = *(const uint4*)((const float*)A1 + (size_t)gr_a * s1 + k0 + col4);
        }
    };
    auto loadB = [&](int k0) {
        if (!bact) return;
        size_t idx = (size_t)(k0 + brow) * BM + bcol;
        if (mode) {
            pb1[0] = *(const uint4*)((const u16*)B1 + idx);
        } else {
            const float* f = (const float*)B1 + idx;
            pb1[0] = *(const uint4*)f;
            pb1[1] = *(const uint4*)(f + 4);
        }
        if constexpr (HASB2) {
            if (mode) {
                pb2[0] = *(const uint4*)((const u16*)B2 + idx);
            } else {
                const float* f = (const float*)B2 + idx;
                pb2[0] = *(const uint4*)f;
                pb2[1] = *(const uint4*)(f + 4);
            }
        }
    };
    auto stage = [&](int k0) {
        float av[4] = {0.f, 0.f, 0.f, 0.f};
        if (gr_a < N) {
            if (k0 >= 128 || amode) {
                av[0] = bf2f((u16)(pa2.x & 0xffff)); av[1] = bf2f((u16)(pa2.x >> 16));
                av[2] = bf2f((u16)(pa2.y & 0xffff)); av[3] = bf2f((u16)(pa2.y >> 16));
            } else {
                const float* f = (const float*)&pa;
#pragma unroll
                for (int i = 0; i < 4; i++) av[i] = f[i];
            }
        }
#pragma unroll
        for (int i = 0; i < 4; i++) As[col4 + i][arow] = av[i];
        if (bact) {
            float bv[8];
            if (mode) unpack8(pb1[0], bv);
            else {
                const float* f = (const float*)pb1;
#pragma unroll
                for (int i = 0; i < 8; i++) bv[i] = f[i];
            }
            *(float4*)&Bs1[brow][bcol] = make_float4(bv[0], bv[1], bv[2], bv[3]);
            *(float4*)&Bs1[brow][bcol + 4] = make_float4(bv[4], bv[5], bv[6], bv[7]);
            if constexpr (HASB2) {
                if (mode) unpack8(pb2[0], bv);
                else {
                    const float* f = (const float*)pb2;
#pragma unroll
                    for (int i = 0; i < 8; i++) bv[i] = f[i];
                }
                *(float4*)&Bs2[brow][bcol] = make_float4(bv[0], bv[1], bv[2], bv[3]);
                *(float4*)&Bs2[brow][bcol + 4] = make_float4(bv[4], bv[5], bv[6], bv[7]);
            }
        }
    };

    float acc1[4][2 * NG], acc2[4][2 * NG];
#pragma unroll
    for (int r = 0; r < 4; r++)
#pragma unroll
        for (int c = 0; c < 2 * NG; c++) { acc1[r][c] = 0.f; acc2[r][c] = 0.f; }

    loadA(0);
    loadB(0);
    for (int k0 = 0; k0 < K; k0 += 16) {
        stage(k0);
        __syncthreads();
        if (k0 + 16 < K) {   // prefetch next tile under the FMAs
            loadA(k0 + 16);
            loadB(k0 + 16);
        }
#pragma unroll
        for (int kk = 0; kk < 16; kk++) {
            float4 a4 = *(const float4*)&As[kk][ty * 4];
            float a[4] = {a4.x, a4.y, a4.z, a4.w};
            float b1[2 * NG];
#pragma unroll
            for (int g = 0; g < NG; g++)
                *(float2*)&b1[2 * g] = *(const float2*)&Bs1[kk][2 * tx + 32 * g];
#pragma unroll
            for (int r = 0; r < 4; r++)
#pragma unroll
                for (int c = 0; c < 2 * NG; c++) acc1[r][c] = fmaf(a[r], b1[c], acc1[r][c]);
            if constexpr (HASB2) {
                float b2[2 * NG];
#pragma unroll
                for (int g = 0; g < NG; g++)
                    *(float2*)&b2[2 * g] = *(const float2*)&Bs2[kk][2 * tx + 32 * g];
#pragma unroll
                for (int r = 0; r < 4; r++)
#pragma unroll
                    for (int c = 0; c < 2 * NG; c++) acc2[r][c] = fmaf(a[r], b2[c], acc2[r][c]);
            }
        }
        __syncthreads();
    }

    // ---- epilogue: C stores + fused el/er ----
    float alv[2 * NG], arv[2 * NG];
#pragma unroll
    for (int g = 0; g < NG; g++)
#pragma unroll
        for (int u = 0; u < 2; u++) {
            int col = 2 * tx + 32 * g + u;
            alv[2 * g + u] = ldf(al, col, mode);
            arv[2 * g + u] = ldf(ar, col, mode);
        }
#pragma unroll
    for (int r = 0; r < 4; r++) {
        int gr = r0 + ty * 4 + r;
        float e0 = 0.f, e1 = 0.f, q0 = 0.f, q1 = 0.f;
#pragma unroll
        for (int g = 0; g < NG; g++)
#pragma unroll
            for (int u = 0; u < 2; u++) {
                float v = acc1[r][2 * g + u];
                if (g < NG / 2) { e0 += v * alv[2 * g + u]; q0 += v * arv[2 * g + u]; }
                else            { e1 += v * alv[2 * g + u]; q1 += v * arv[2 * g + u]; }
            }
#pragma unroll
        for (int o = 1; o <= 8; o <<= 1) {   // reduce across the 16 tx lanes
            e0 += __shfl_xor(e0, o, 64); e1 += __shfl_xor(e1, o, 64);
            q0 += __shfl_xor(q0, o, 64); q1 += __shfl_xor(q1, o, 64);
        }
        if (gr < N) {
#pragma unroll
            for (int g = 0; g < NG; g++) {
                *(float2*)&C1[(size_t)gr * BM + 2 * tx + 32 * g] =
                    make_float2(acc1[r][2 * g], acc1[r][2 * g + 1]);
                if constexpr (HASB2) {
                    *(u32*)&C2[(size_t)gr * BM + 2 * tx + 32 * g] =
                        pack2(acc2[r][2 * g], acc2[r][2 * g + 1]);
                }
            }
            if (tx == 0) *(float4*)&att[(size_t)gr * 4] = make_float4(e0, e1, q0, q1);
        }
    }
}

// ---------------- edge aggregation: one wave per (node, head) ----------------
// Chunked exact softmax; phase2 4-wide unrolled (independent partial sums).
// res/outf alias (same element). final_mean: heads combined via block LDS.
__global__ void k_edge_gat(const int* __restrict__ off, const int* __restrict__ ssrc,
                           const float* __restrict__ h, const float* __restrict__ att,
                           const u16* res, u16* outf, float* outs,
                           int N, int final_mean) {
    __shared__ float pbuf[4][64];
    __shared__ int sbuf[4][64];
    __shared__ float xbuf[4][64];
    int wv = threadIdx.x >> 6;
    int lane = threadIdx.x & 63;
    int node = blockIdx.x * 2 + (wv >> 1);
    int head = wv & 1;
    int valid = node < N;
    int beg = 0, end = 0;
    float er = 0.f;
    if (valid) {
        beg = off[node]; end = off[node + 1];
        er = att[(size_t)node * 4 + 2 + head];
    }
    float m = -1e30f, d = 0.f, O = 0.f;
    size_t hb = (size_t)64 * head + lane;
    for (int c = beg; c < end; c += 64) {
        int cn = min(end - c, 64);
        int s = 0;
        float x = -1e30f;
        if (lane < cn) {
            s = ssrc[c + lane];
            x = lrelu(att[(size_t)s * 4 + head] + er);
        }
        float cm = x;
#pragma unroll
        for (int o = 32; o; o >>= 1) cm = fmaxf(cm, __shfl_xor(cm, o, 64));
        float nm = fmaxf(m, cm);
        float p = (lane < cn) ? __expf(x - nm) : 0.f;
        float cd = p;
#pragma unroll
        for (int o = 32; o; o >>= 1) cd += __shfl_xor(cd, o, 64);
        float sc = __expf(m - nm);
        d = d * sc + cd;
        O *= sc;
        m = nm;
        pbuf[wv][lane] = p;
        sbuf[wv][lane] = s;
        float Oa = 0.f, Ob = 0.f, Oc = 0.f, Od = 0.f;
        int j = 0;
        for (; j + 3 < cn; j += 4) {
            int s0 = sbuf[wv][j], s1 = sbuf[wv][j + 1];
            int s2 = sbuf[wv][j + 2], s3 = sbuf[wv][j + 3];
            float p0 = pbuf[wv][j], p1 = pbuf[wv][j + 1];
            float p2 = pbuf[wv][j + 2], p3 = pbuf[wv][j + 3];
            Oa += p0 * h[(size_t)s0 * 128 + hb];
            Ob += p1 * h[(size_t)s1 * 128 + hb];
            Oc += p2 * h[(size_t)s2 * 128 + hb];
            Od += p3 * h[(size_t)s3 * 128 + hb];
        }
        for (; j < cn; j++)
            Oa += pbuf[wv][j] * h[(size_t)sbuf[wv][j] * 128 + hb];
        O += (Oa + Ob) + (Oc + Od);
    }
    float a = 0.f;
    if (valid) {
        float o = (end > beg) ? O / d : 0.f;
        a = o + bf2f(res[(size_t)node * 128 + hb]);
        a = a > 0.f ? a : (__expf(a) - 1.f);  // elu
    }
    if (final_mean) {
        xbuf[wv][lane] = a;
        __syncthreads();
        if (valid && head == 0)
            outs[(size_t)node * 64 + lane] = 0.5f * (a + xbuf[wv + 1][lane]);
    } else if (valid) {
        outf[(size_t)node * 128 + hb] = f2bf(a);
    }
}

__global__ void k_edge_pg(const int* __restrict__ off, const int* __restrict__ ssrc,
                          const float* __restrict__ h, const float* __restrict__ att,
                          u16* hp, int N) {
    __shared__ float pbuf[4][2][64];
    __shared__ int sbuf[4][64];
    int wv = threadIdx.x >> 6;
    int node = blockIdx.x * 4 + wv;
    int lane = threadIdx.x & 63;
    if (node >= N) return;
    int head = lane >> 5;
    int beg = off[node], end = off[node + 1];
    float4 a4 = *(const float4*)&att[(size_t)node * 4];
    float er0 = a4.z, er1 = a4.w;
    float m0 = -1e30f, m1 = -1e30f, d0 = 0.f, d1 = 0.f, O = 0.f;
    for (int c = beg; c < end; c += 64) {
        int cn = min(end - c, 64);
        int s = 0;
        float x0 = -1e30f, x1 = -1e30f;
        if (lane < cn) {
            s = ssrc[c + lane];
            float2 e = *(const float2*)&att[(size_t)s * 4];
            x0 = lrelu(e.x + er0);
            x1 = lrelu(e.y + er1);
        }
        float cm0 = x0, cm1 = x1;
#pragma unroll
        for (int o = 32; o; o >>= 1) {
            cm0 = fmaxf(cm0, __shfl_xor(cm0, o, 64));
            cm1 = fmaxf(cm1, __shfl_xor(cm1, o, 64));
        }
        float nm0 = fmaxf(m0, cm0), nm1 = fmaxf(m1, cm1);
        float p0 = (lane < cn) ? __expf(x0 - nm0) : 0.f;
        float p1 = (lane < cn) ? __expf(x1 - nm1) : 0.f;
        float cd0 = p0, cd1 = p1;
#pragma unroll
        for (int o = 32; o; o >>= 1) {
            cd0 += __shfl_xor(cd0, o, 64);
            cd1 += __shfl_xor(cd1, o, 64);
        }
        float sc0 = __expf(m0 - nm0), sc1 = __expf(m1 - nm1);
        d0 = d0 * sc0 + cd0; d1 = d1 * sc1 + cd1;
        O *= head ? sc1 : sc0;
        m0 = nm0; m1 = nm1;
        pbuf[wv][0][lane] = p0;
        pbuf[wv][1][lane] = p1;
        sbuf[wv][lane] = s;
        float Oa = 0.f, Ob = 0.f;
        int j = 0;
        for (; j + 3 < cn; j += 4) {
            int s0 = sbuf[wv][j], s1 = sbuf[wv][j + 1];
            int s2 = sbuf[wv][j + 2], s3 = sbuf[wv][j + 3];
            float p0v = pbuf[wv][head][j], p1v = pbuf[wv][head][j + 1];
            float p2v = pbuf[wv][head][j + 2], p3v = pbuf[wv][head][j + 3];
            Oa += p0v * h[(size_t)s0 * 64 + lane] + p1v * h[(size_t)s1 * 64 + lane];
            Ob += p2v * h[(size_t)s2 * 64 + lane] + p3v * h[(size_t)s3 * 64 + lane];
        }
        for (; j < cn; j++)
            Oa += pbuf[wv][head][j] * h[(size_t)sbuf[wv][j] * 64 + lane];
        O += Oa + Ob;
    }
    float dh = head ? d1 : d0;
    float o = (end > beg) ? O / dh : 0.f;
    float a = tanhf(o + bf2f(hp[(size_t)node * 64 + lane]));
    hp[(size_t)node * 64 + lane] = f2bf(a);
}

// ---------------- launch ----------------
extern "C" void kernel_launch(void* const* d_in, const int* in_sizes, int n_in,
                              void* d_out, int out_size, void* d_ws, size_t ws_size,
                              hipStream_t stream) {
    const int N = NN, E = NE;
    const void* fvs = d_in[0];
    const void* pos = d_in[1];
    const int* src = (const int*)d_in[2];
    const int* dst = (const int*)d_in[3];
    const void* gW[3]  = {d_in[4],  d_in[8],  d_in[12]};
    const void* gal[3] = {d_in[5],  d_in[9],  d_in[13]};
    const void* gar[3] = {d_in[6],  d_in[10], d_in[14]};
    const void* grW[3] = {d_in[7],  d_in[11], d_in[15]};
    const void* pW[2]  = {d_in[16], d_in[19]};
    const void* pal[2] = {d_in[17], d_in[20]};
    const void* par[2] = {d_in[18], d_in[21]};

    // ---- workspace layout (wrap-safe) ----
    auto al256 = [](size_t b) { return (b + 255) & ~(size_t)255; };
    size_t sz_dmode = al256(4);
    size_t sz_att   = al256((size_t)N * 4 * 4);   // also hosts cnt/cnt2 during CSR build
    size_t sz_off   = al256((size_t)(N + 1) * 4);
    size_t sz_ssrc  = al256((size_t)E * 4);
    size_t sz_hs    = al256((size_t)N * 128 * 2);
    size_t sz_hp    = al256((size_t)N * 64 * 2);
    size_t need = sz_dmode + sz_att + sz_off + sz_ssrc + sz_hs + sz_hp;  // ~23 MB
    int bad = (need > ws_size) ? 1 : 0;

    size_t cur = 0;
    auto alloc = [&](size_t bytes) {
        if (cur + bytes > ws_size) cur = 0;
        char* p = (char*)d_ws + cur;
        if (bytes <= ws_size) cur += bytes;
        return p;
    };
    int* dmode  = (int*)alloc(sz_dmode);
    float* att  = (float*)alloc(sz_att);
    int* off    = (int*)alloc(sz_off);
    int* ssrc   = (int*)alloc(sz_ssrc);
    u16* hs     = (u16*)alloc(sz_hs);
    u16* hp     = (u16*)alloc(sz_hp);

    // cnt/cnt2 alias att (CSR build completes before att's first write; 800KB >= 400KB)
    int* cnt  = (int*)att;
    int* cnt2 = (int*)((char*)att + al256((size_t)N * 4));

    float* H = (float*)d_out;  // transformed features [N,128] f32 in d_out, dead at end

    hipMemsetAsync(cnt, 0, (size_t)N * 4, stream);
    hipMemsetAsync(cnt2, 0, (size_t)N * 4, stream);

    k_detect<<<1, 256, 0, stream>>>((const u16*)fvs, dmode);

    int eb = (E + 255) / 256;
    k_hist<<<eb, 256, 0, stream>>>(dst, cnt, E);
    k_scan<<<1, 1024, 0, stream>>>(cnt, off, N);
    k_fill<<<eb, 256, 0, stream>>>(src, dst, off, cnt2, ssrc, E);

    k_init<<<(N * 64 + 255) / 256, 256, 0, stream>>>(pos, hp, dmode, N * 64);

    int gb = (N + 63) / 64;
    int nb = (N + 3) / 4;     // edge_pg: 4 nodes/block
    int nb2 = (N + 1) / 2;    // edge_gat: 2 nodes/block (wave per node-head)

    // ---- layer 0 ----
    k_gemm<128, true><<<gb, 256, 0, stream>>>(fvs, hp, gW[0], grW[0], H, hs, att, gal[0], gar[0], N, 192, 128, dmode, 1);
    k_edge_gat<<<nb2, 256, 0, stream>>>(off, ssrc, H, att, hs, hs, nullptr, N, 0);
    k_gemm<64, false><<<gb, 256, 0, stream>>>(hp, nullptr, pW[0], nullptr, H, nullptr, att, pal[0], par[0], N, 64, 64, dmode, 0);
    k_edge_pg<<<nb, 256, 0, stream>>>(off, ssrc, H, att, hp, N);

    // ---- layer 1 ----
    k_gemm<128, true><<<gb, 256, 0, stream>>>(hs, hp, gW[1], grW[1], H, hs, att, gal[1], gar[1], N, 192, 128, dmode, 0);
    k_edge_gat<<<nb2, 256, 0, stream>>>(off, ssrc, H, att, hs, hs, nullptr, N, 0);
    k_gemm<64, false><<<gb, 256, 0, stream>>>(hp, nullptr, pW[1], nullptr, H, nullptr, att, pal[1], par[1], N, 64, 64, dmode, 0);
    k_edge_pg<<<nb, 256, 0, stream>>>(off, ssrc, H, att, hp, N);  // hp = pg1 out (tanh)

    // ---- output layer ----
    k_gemm<128, true><<<gb, 256, 0, stream>>>(hs, hp, gW[2], grW[2], H, hs, att, gal[2], gar[2], N, 192, 128, dmode, 0);
    // final mean written in-place into hs rows as f32 (row = 256B = 64 floats)
    k_edge_gat<<<nb2, 256, 0, stream>>>(off, ssrc, H, att, hs, nullptr, (float*)hs, N, 1);

    // H (= d_out) now dead; materialize outputs as f32.
    hipMemcpyAsync((float*)d_out, (float*)hs, (size_t)N * 64 * 4, hipMemcpyDeviceToDevice, stream);
    k_cvt<<<(N * 64 + 255) / 256, 256, 0, stream>>>(hp, (float*)d_out + (size_t)N * 64, N * 64);

    // Diagnostic: if workspace too small, out[0] reads ~100000 + MB*1000.
    if (bad) {
        float v = 100000.f + 1000.f * (float)(ws_size >> 20);
        k_tracer<<<1, 64, 0, stream>>>((float*)d_out, v);
    }
}

// Round 8
// 914.871 us; speedup vs baseline: 1.2449x; 1.2449x over previous
//
#include <hip/hip_runtime.h>
#include <hip/hip_bf16.h>

#define NN 50000
#define NE 800000

typedef unsigned short u16;
typedef unsigned int u32;

__device__ __forceinline__ float bf2f(u16 u) {
    u32 x = ((u32)u) << 16;
    return __uint_as_float(x);
}
__device__ __forceinline__ u16 f2bf(float f) {
    u32 x = __float_as_uint(f);
    u32 r = (x + 0x7fffu + ((x >> 16) & 1u)) >> 16;  // round-nearest-even
    return (u16)r;
}
__device__ __forceinline__ u32 pack2(float a, float b) {
    return (u32)f2bf(a) | ((u32)f2bf(b) << 16);
}
__device__ __forceinline__ void unpack8(uint4 u, float* o) {
    o[0] = bf2f((u16)(u.x & 0xffff)); o[1] = bf2f((u16)(u.x >> 16));
    o[2] = bf2f((u16)(u.y & 0xffff)); o[3] = bf2f((u16)(u.y >> 16));
    o[4] = bf2f((u16)(u.z & 0xffff)); o[5] = bf2f((u16)(u.z >> 16));
    o[6] = bf2f((u16)(u.w & 0xffff)); o[7] = bf2f((u16)(u.w >> 16));
}
__device__ __forceinline__ float ldf(const void* p, size_t idx, int mode) {
    return mode ? bf2f(((const u16*)p)[idx]) : ((const float*)p)[idx];
}
__device__ __forceinline__ float lrelu(float x) { return x > 0.f ? x : 0.2f * x; }

// ---------------- diagnostics ----------------
__global__ void k_tracer(float* out, float v) {
    if (threadIdx.x == 0 && blockIdx.x == 0) out[0] = v;
}

// ---------------- dtype detect (0 = f32 inputs, 1 = bf16 inputs) ----------------
__global__ void k_detect(const u16* __restrict__ fvs, int* __restrict__ mode) {
    __shared__ int cnt[256];
    int t = threadIdx.x;
    int bad = 0;
    for (int i = 0; i < 16; i++) {
        u16 u = fvs[(size_t)(t * 16 + i) * 2];
        int e = (u >> 7) & 0xff;
        if (e == 255 || e >= 134 || e <= 100) bad++;
    }
    cnt[t] = bad;
    __syncthreads();
    for (int d = 128; d; d >>= 1) {
        if (t < d) cnt[t] += cnt[t + d];
        __syncthreads();
    }
    if (t == 0) *mode = (cnt[0] > 2048) ? 0 : 1;
}

// ---------------- CSR build ----------------
__global__ void k_hist(const int* __restrict__ dst, int* __restrict__ cnt, int E) {
    int e = blockIdx.x * blockDim.x + threadIdx.x;
    if (e < E) atomicAdd(&cnt[dst[e]], 1);
}

__global__ void k_scan(const int* __restrict__ cnt, int* __restrict__ off, int N) {
    __shared__ int sums[1024];
    int t = threadIdx.x;
    int chunk = (N + 1023) >> 10;
    int b = t * chunk;
    int s = 0;
    for (int i = 0; i < chunk; i++) { int idx = b + i; if (idx < N) s += cnt[idx]; }
    sums[t] = s;
    __syncthreads();
    for (int d = 1; d < 1024; d <<= 1) {
        int v = (t >= d) ? sums[t - d] : 0;
        __syncthreads();
        sums[t] += v;
        __syncthreads();
    }
    int run = (t == 0) ? 0 : sums[t - 1];
    for (int i = 0; i < chunk; i++) {
        int idx = b + i;
        if (idx < N) { off[idx] = run; run += cnt[idx]; }
    }
    if (t == 1023) off[N] = sums[1023];
}

__global__ void k_fill(const int* __restrict__ src, const int* __restrict__ dst,
                       const int* __restrict__ off, int* __restrict__ cnt2,
                       int* __restrict__ ssrc, int E) {
    int e = blockIdx.x * blockDim.x + threadIdx.x;
    if (e < E) {
        int d = dst[e];
        int p = off[d] + atomicAdd(&cnt2[d], 1);
        ssrc[p] = src[e];
    }
}

// ---------------- init: hp = bf16(pos) ----------------
__global__ void k_init(const void* __restrict__ pos, u16* __restrict__ hp,
                       const int* __restrict__ dmode, int n64) {
    int i = blockIdx.x * blockDim.x + threadIdx.x;
    if (i >= n64) return;
    int mode = *dmode;
    hp[i] = mode ? ((const u16*)pos)[i] : f2bf(((const float*)pos)[i]);
}

// ---------------- hp (bf16) -> f32 ----------------
__global__ void k_cvt(const u16* __restrict__ in, float* __restrict__ out, int n) {
    int i = blockIdx.x * blockDim.x + threadIdx.x;
    if (i < n) out[i] = bf2f(in[i]);
}

// ---------------- GEMM (BK=16) + fused el/er epilogue ----------------
// C1[N,BM](f32), C2[N,BM](bf16) = [A1|A2][N,K] x B1/B2[K,BM]
// BK=16 keeps LDS ~21KB (LDS cap 7 blocks/CU); plain launch_bounds lets the
// compiler take ~128 VGPRs (VGPR cap 4 blocks/CU) with NO accumulator spill
// (R7's (256,4) hint forced 64 VGPRs -> 570 MB/dispatch scratch traffic).
// A1 and C2 may alias (in-place): block touches only its own 64 rows.
template <int BM, bool HASB2>
__launch_bounds__(256)
__global__ void k_gemm(const void* A1, const u16* __restrict__ A2,
                       const void* __restrict__ B1, const void* __restrict__ B2,
                       float* __restrict__ C1, u16* C2, float* __restrict__ att,
                       const void* __restrict__ al, const void* __restrict__ ar,
                       int N, int K, int s1, const int* __restrict__ dmode,
                       int a1_input) {
    constexpr int NG = BM / 32;      // col pair-groups per thread (4 or 2)
    constexpr int BPR = BM / 8;      // 8-float chunks per B row
    __shared__ alignas(16) float As[16][68];
    __shared__ alignas(16) float Bs1[16][BM + 4];
    __shared__ alignas(16) float Bs2[HASB2 ? 16 : 1][HASB2 ? BM + 4 : 1];

    int mode = *dmode;
    int amode = a1_input ? mode : 1;
    int tid = threadIdx.x;
    int tx = tid & 15, ty = tid >> 4;
    int r0 = blockIdx.x * 64;
    int arow = tid >> 2, col4 = (tid & 3) * 4;
    int gr_a = r0 + arow;

    bool bact = tid < 2 * BM;        // B staging: 2*BM chunks of 8 floats
    int brow = tid / BPR, bcol = (tid % BPR) * 8;

    uint4 pa; uint2 pa2; uint4 pb1[2], pb2[2];

    auto loadA = [&](int k0) {
        if (gr_a >= N) return;
        if (k0 >= 128) {
            pa2 = *(const uint2*)&A2[(size_t)gr_a * 64 + (k0 - 128) + col4];
        } else if (amode) {
            pa2 = *(const uint2*)((const u16*)A1 + (size_t)gr_a * s1 + k0 + col4);
        } else {
            pa = *(const uint4*)((const float*)A1 + (size_t)gr_a * s1 + k0 + col4);
        }
    };
    auto loadB = [&](int k0) {
        if (!bact) return;
        size_t idx = (size_t)(k0 + brow) * BM + bcol;
        if (mode) {
            pb1[0] = *(const uint4*)((const u16*)B1 + idx);
        } else {
            const float* f = (const float*)B1 + idx;
            pb1[0] = *(const uint4*)f;
            pb1[1] = *(const uint4*)(f + 4);
        }
        if constexpr (HASB2) {
            if (mode) {
                pb2[0] = *(const uint4*)((const u16*)B2 + idx);
            } else {
                const float* f = (const float*)B2 + idx;
                pb2[0] = *(const uint4*)f;
                pb2[1] = *(const uint4*)(f + 4);
            }
        }
    };
    auto stage = [&](int k0) {
        float av[4] = {0.f, 0.f, 0.f, 0.f};
        if (gr_a < N) {
            if (k0 >= 128 || amode) {
                av[0] = bf2f((u16)(pa2.x & 0xffff)); av[1] = bf2f((u16)(pa2.x >> 16));
                av[2] = bf2f((u16)(pa2.y & 0xffff)); av[3] = bf2f((u16)(pa2.y >> 16));
            } else {
                const float* f = (const float*)&pa;
#pragma unroll
                for (int i = 0; i < 4; i++) av[i] = f[i];
            }
        }
#pragma unroll
        for (int i = 0; i < 4; i++) As[col4 + i][arow] = av[i];
        if (bact) {
            float bv[8];
            if (mode) unpack8(pb1[0], bv);
            else {
                const float* f = (const float*)pb1;
#pragma unroll
                for (int i = 0; i < 8; i++) bv[i] = f[i];
            }
            *(float4*)&Bs1[brow][bcol] = make_float4(bv[0], bv[1], bv[2], bv[3]);
            *(float4*)&Bs1[brow][bcol + 4] = make_float4(bv[4], bv[5], bv[6], bv[7]);
            if constexpr (HASB2) {
                if (mode) unpack8(pb2[0], bv);
                else {
                    const float* f = (const float*)pb2;
#pragma unroll
                    for (int i = 0; i < 8; i++) bv[i] = f[i];
                }
                *(float4*)&Bs2[brow][bcol] = make_float4(bv[0], bv[1], bv[2], bv[3]);
                *(float4*)&Bs2[brow][bcol + 4] = make_float4(bv[4], bv[5], bv[6], bv[7]);
            }
        }
    };

    float acc1[4][2 * NG], acc2[4][2 * NG];
#pragma unroll
    for (int r = 0; r < 4; r++)
#pragma unroll
        for (int c = 0; c < 2 * NG; c++) { acc1[r][c] = 0.f; acc2[r][c] = 0.f; }

    loadA(0);
    loadB(0);
    for (int k0 = 0; k0 < K; k0 += 16) {
        stage(k0);
        __syncthreads();
        if (k0 + 16 < K) {   // prefetch next tile under the FMAs
            loadA(k0 + 16);
            loadB(k0 + 16);
        }
#pragma unroll
        for (int kk = 0; kk < 16; kk++) {
            float4 a4 = *(const float4*)&As[kk][ty * 4];
            float a[4] = {a4.x, a4.y, a4.z, a4.w};
            float b1[2 * NG];
#pragma unroll
            for (int g = 0; g < NG; g++)
                *(float2*)&b1[2 * g] = *(const float2*)&Bs1[kk][2 * tx + 32 * g];
#pragma unroll
            for (int r = 0; r < 4; r++)
#pragma unroll
                for (int c = 0; c < 2 * NG; c++) acc1[r][c] = fmaf(a[r], b1[c], acc1[r][c]);
            if constexpr (HASB2) {
                float b2[2 * NG];
#pragma unroll
                for (int g = 0; g < NG; g++)
                    *(float2*)&b2[2 * g] = *(const float2*)&Bs2[kk][2 * tx + 32 * g];
#pragma unroll
                for (int r = 0; r < 4; r++)
#pragma unroll
                    for (int c = 0; c < 2 * NG; c++) acc2[r][c] = fmaf(a[r], b2[c], acc2[r][c]);
            }
        }
        __syncthreads();
    }

    // ---- epilogue: C stores + fused el/er ----
    float alv[2 * NG], arv[2 * NG];
#pragma unroll
    for (int g = 0; g < NG; g++)
#pragma unroll
        for (int u = 0; u < 2; u++) {
            int col = 2 * tx + 32 * g + u;
            alv[2 * g + u] = ldf(al, col, mode);
            arv[2 * g + u] = ldf(ar, col, mode);
        }
#pragma unroll
    for (int r = 0; r < 4; r++) {
        int gr = r0 + ty * 4 + r;
        float e0 = 0.f, e1 = 0.f, q0 = 0.f, q1 = 0.f;
#pragma unroll
        for (int g = 0; g < NG; g++)
#pragma unroll
            for (int u = 0; u < 2; u++) {
                float v = acc1[r][2 * g + u];
                if (g < NG / 2) { e0 += v * alv[2 * g + u]; q0 += v * arv[2 * g + u]; }
                else            { e1 += v * alv[2 * g + u]; q1 += v * arv[2 * g + u]; }
            }
#pragma unroll
        for (int o = 1; o <= 8; o <<= 1) {   // reduce across the 16 tx lanes
            e0 += __shfl_xor(e0, o, 64); e1 += __shfl_xor(e1, o, 64);
            q0 += __shfl_xor(q0, o, 64); q1 += __shfl_xor(q1, o, 64);
        }
        if (gr < N) {
#pragma unroll
            for (int g = 0; g < NG; g++) {
                *(float2*)&C1[(size_t)gr * BM + 2 * tx + 32 * g] =
                    make_float2(acc1[r][2 * g], acc1[r][2 * g + 1]);
                if constexpr (HASB2) {
                    *(u32*)&C2[(size_t)gr * BM + 2 * tx + 32 * g] =
                        pack2(acc2[r][2 * g], acc2[r][2 * g + 1]);
                }
            }
            if (tx == 0) *(float4*)&att[(size_t)gr * 4] = make_float4(e0, e1, q0, q1);
        }
    }
}

// ---------------- edge aggregation: one wave per (node, head) ----------------
// Chunked exact softmax; phase2 4-wide unrolled (independent partial sums).
// res/outf alias (same element). final_mean: heads combined via block LDS.
__global__ void k_edge_gat(const int* __restrict__ off, const int* __restrict__ ssrc,
                           const float* __restrict__ h, const float* __restrict__ att,
                           const u16* res, u16* outf, float* outs,
                           int N, int final_mean) {
    __shared__ float pbuf[4][64];
    __shared__ int sbuf[4][64];
    __shared__ float xbuf[4][64];
    int wv = threadIdx.x >> 6;
    int lane = threadIdx.x & 63;
    int node = blockIdx.x * 2 + (wv >> 1);
    int head = wv & 1;
    int valid = node < N;
    int beg = 0, end = 0;
    float er = 0.f;
    if (valid) {
        beg = off[node]; end = off[node + 1];
        er = att[(size_t)node * 4 + 2 + head];
    }
    float m = -1e30f, d = 0.f, O = 0.f;
    size_t hb = (size_t)64 * head + lane;
    for (int c = beg; c < end; c += 64) {
        int cn = min(end - c, 64);
        int s = 0;
        float x = -1e30f;
        if (lane < cn) {
            s = ssrc[c + lane];
            x = lrelu(att[(size_t)s * 4 + head] + er);
        }
        float cm = x;
#pragma unroll
        for (int o = 32; o; o >>= 1) cm = fmaxf(cm, __shfl_xor(cm, o, 64));
        float nm = fmaxf(m, cm);
        float p = (lane < cn) ? __expf(x - nm) : 0.f;
        float cd = p;
#pragma unroll
        for (int o = 32; o; o >>= 1) cd += __shfl_xor(cd, o, 64);
        float sc = __expf(m - nm);
        d = d * sc + cd;
        O *= sc;
        m = nm;
        pbuf[wv][lane] = p;
        sbuf[wv][lane] = s;
        float Oa = 0.f, Ob = 0.f, Oc = 0.f, Od = 0.f;
        int j = 0;
        for (; j + 3 < cn; j += 4) {
            int s0 = sbuf[wv][j], s1 = sbuf[wv][j + 1];
            int s2 = sbuf[wv][j + 2], s3 = sbuf[wv][j + 3];
            float p0 = pbuf[wv][j], p1 = pbuf[wv][j + 1];
            float p2 = pbuf[wv][j + 2], p3 = pbuf[wv][j + 3];
            Oa += p0 * h[(size_t)s0 * 128 + hb];
            Ob += p1 * h[(size_t)s1 * 128 + hb];
            Oc += p2 * h[(size_t)s2 * 128 + hb];
            Od += p3 * h[(size_t)s3 * 128 + hb];
        }
        for (; j < cn; j++)
            Oa += pbuf[wv][j] * h[(size_t)sbuf[wv][j] * 128 + hb];
        O += (Oa + Ob) + (Oc + Od);
    }
    float a = 0.f;
    if (valid) {
        float o = (end > beg) ? O / d : 0.f;
        a = o + bf2f(res[(size_t)node * 128 + hb]);
        a = a > 0.f ? a : (__expf(a) - 1.f);  // elu
    }
    if (final_mean) {
        xbuf[wv][lane] = a;
        __syncthreads();
        if (valid && head == 0)
            outs[(size_t)node * 64 + lane] = 0.5f * (a + xbuf[wv + 1][lane]);
    } else if (valid) {
        outf[(size_t)node * 128 + hb] = f2bf(a);
    }
}

__global__ void k_edge_pg(const int* __restrict__ off, const int* __restrict__ ssrc,
                          const float* __restrict__ h, const float* __restrict__ att,
                          u16* hp, int N) {
    __shared__ float pbuf[4][2][64];
    __shared__ int sbuf[4][64];
    int wv = threadIdx.x >> 6;
    int node = blockIdx.x * 4 + wv;
    int lane = threadIdx.x & 63;
    if (node >= N) return;
    int head = lane >> 5;
    int beg = off[node], end = off[node + 1];
    float4 a4 = *(const float4*)&att[(size_t)node * 4];
    float er0 = a4.z, er1 = a4.w;
    float m0 = -1e30f, m1 = -1e30f, d0 = 0.f, d1 = 0.f, O = 0.f;
    for (int c = beg; c < end; c += 64) {
        int cn = min(end - c, 64);
        int s = 0;
        float x0 = -1e30f, x1 = -1e30f;
        if (lane < cn) {
            s = ssrc[c + lane];
            float2 e = *(const float2*)&att[(size_t)s * 4];
            x0 = lrelu(e.x + er0);
            x1 = lrelu(e.y + er1);
        }
        float cm0 = x0, cm1 = x1;
#pragma unroll
        for (int o = 32; o; o >>= 1) {
            cm0 = fmaxf(cm0, __shfl_xor(cm0, o, 64));
            cm1 = fmaxf(cm1, __shfl_xor(cm1, o, 64));
        }
        float nm0 = fmaxf(m0, cm0), nm1 = fmaxf(m1, cm1);
        float p0 = (lane < cn) ? __expf(x0 - nm0) : 0.f;
        float p1 = (lane < cn) ? __expf(x1 - nm1) : 0.f;
        float cd0 = p0, cd1 = p1;
#pragma unroll
        for (int o = 32; o; o >>= 1) {
            cd0 += __shfl_xor(cd0, o, 64);
            cd1 += __shfl_xor(cd1, o, 64);
        }
        float sc0 = __expf(m0 - nm0), sc1 = __expf(m1 - nm1);
        d0 = d0 * sc0 + cd0; d1 = d1 * sc1 + cd1;
        O *= head ? sc1 : sc0;
        m0 = nm0; m1 = nm1;
        pbuf[wv][0][lane] = p0;
        pbuf[wv][1][lane] = p1;
        sbuf[wv][lane] = s;
        float Oa = 0.f, Ob = 0.f;
        int j = 0;
        for (; j + 3 < cn; j += 4) {
            int s0 = sbuf[wv][j], s1 = sbuf[wv][j + 1];
            int s2 = sbuf[wv][j + 2], s3 = sbuf[wv][j + 3];
            float p0v = pbuf[wv][head][j], p1v = pbuf[wv][head][j + 1];
            float p2v = pbuf[wv][head][j + 2], p3v = pbuf[wv][head][j + 3];
            Oa += p0v * h[(size_t)s0 * 64 + lane] + p1v * h[(size_t)s1 * 64 + lane];
            Ob += p2v * h[(size_t)s2 * 64 + lane] + p3v * h[(size_t)s3 * 64 + lane];
        }
        for (; j < cn; j++)
            Oa += pbuf[wv][head][j] * h[(size_t)sbuf[wv][j] * 64 + lane];
        O += Oa + Ob;
    }
    float dh = head ? d1 : d0;
    float o = (end > beg) ? O / dh : 0.f;
    float a = tanhf(o + bf2f(hp[(size_t)node * 64 + lane]));
    hp[(size_t)node * 64 + lane] = f2bf(a);
}

// ---------------- launch ----------------
extern "C" void kernel_launch(void* const* d_in, const int* in_sizes, int n_in,
                              void* d_out, int out_size, void* d_ws, size_t ws_size,
                              hipStream_t stream) {
    const int N = NN, E = NE;
    const void* fvs = d_in[0];
    const void* pos = d_in[1];
    const int* src = (const int*)d_in[2];
    const int* dst = (const int*)d_in[3];
    const void* gW[3]  = {d_in[4],  d_in[8],  d_in[12]};
    const void* gal[3] = {d_in[5],  d_in[9],  d_in[13]};
    const void* gar[3] = {d_in[6],  d_in[10], d_in[14]};
    const void* grW[3] = {d_in[7],  d_in[11], d_in[15]};
    const void* pW[2]  = {d_in[16], d_in[19]};
    const void* pal[2] = {d_in[17], d_in[20]};
    const void* par[2] = {d_in[18], d_in[21]};

    // ---- workspace layout (wrap-safe) ----
    auto al256 = [](size_t b) { return (b + 255) & ~(size_t)255; };
    size_t sz_dmode = al256(4);
    size_t sz_att   = al256((size_t)N * 4 * 4);   // also hosts cnt/cnt2 during CSR build
    size_t sz_off   = al256((size_t)(N + 1) * 4);
    size_t sz_ssrc  = al256((size_t)E * 4);
    size_t sz_hs    = al256((size_t)N * 128 * 2);
    size_t sz_hp    = al256((size_t)N * 64 * 2);
    size_t need = sz_dmode + sz_att + sz_off + sz_ssrc + sz_hs + sz_hp;  // ~23 MB
    int bad = (need > ws_size) ? 1 : 0;

    size_t cur = 0;
    auto alloc = [&](size_t bytes) {
        if (cur + bytes > ws_size) cur = 0;
        char* p = (char*)d_ws + cur;
        if (bytes <= ws_size) cur += bytes;
        return p;
    };
    int* dmode  = (int*)alloc(sz_dmode);
    float* att  = (float*)alloc(sz_att);
    int* off    = (int*)alloc(sz_off);
    int* ssrc   = (int*)alloc(sz_ssrc);
    u16* hs     = (u16*)alloc(sz_hs);
    u16* hp     = (u16*)alloc(sz_hp);

    // cnt/cnt2 alias att (CSR build completes before att's first write; 800KB >= 400KB)
    int* cnt  = (int*)att;
    int* cnt2 = (int*)((char*)att + al256((size_t)N * 4));

    float* H = (float*)d_out;  // transformed features [N,128] f32 in d_out, dead at end

    hipMemsetAsync(cnt, 0, (size_t)N * 4, stream);
    hipMemsetAsync(cnt2, 0, (size_t)N * 4, stream);

    k_detect<<<1, 256, 0, stream>>>((const u16*)fvs, dmode);

    int eb = (E + 255) / 256;
    k_hist<<<eb, 256, 0, stream>>>(dst, cnt, E);
    k_scan<<<1, 1024, 0, stream>>>(cnt, off, N);
    k_fill<<<eb, 256, 0, stream>>>(src, dst, off, cnt2, ssrc, E);

    k_init<<<(N * 64 + 255) / 256, 256, 0, stream>>>(pos, hp, dmode, N * 64);

    int gb = (N + 63) / 64;
    int nb = (N + 3) / 4;     // edge_pg: 4 nodes/block
    int nb2 = (N + 1) / 2;    // edge_gat: 2 nodes/block (wave per node-head)

    // ---- layer 0 ----
    k_gemm<128, true><<<gb, 256, 0, stream>>>(fvs, hp, gW[0], grW[0], H, hs, att, gal[0], gar[0], N, 192, 128, dmode, 1);
    k_edge_gat<<<nb2, 256, 0, stream>>>(off, ssrc, H, att, hs, hs, nullptr, N, 0);
    k_gemm<64, false><<<gb, 256, 0, stream>>>(hp, nullptr, pW[0], nullptr, H, nullptr, att, pal[0], par[0], N, 64, 64, dmode, 0);
    k_edge_pg<<<nb, 256, 0, stream>>>(off, ssrc, H, att, hp, N);

    // ---- layer 1 ----
    k_gemm<128, true><<<gb, 256, 0, stream>>>(hs, hp, gW[1], grW[1], H, hs, att, gal[1], gar[1], N, 192, 128, dmode, 0);
    k_edge_gat<<<nb2, 256, 0, stream>>>(off, ssrc, H, att, hs, hs, nullptr, N, 0);
    k_gemm<64, false><<<gb, 256, 0, stream>>>(hp, nullptr, pW[1], nullptr, H, nullptr, att, pal[1], par[1], N, 64, 64, dmode, 0);
    k_edge_pg<<<nb, 256, 0, stream>>>(off, ssrc, H, att, hp, N);  // hp = pg1 out (tanh)

    // ---- output layer ----
    k_gemm<128, true><<<gb, 256, 0, stream>>>(hs, hp, gW[2], grW[2], H, hs, att, gal[2], gar[2], N, 192, 128, dmode, 0);
    // final mean written in-place into hs rows as f32 (row = 256B = 64 floats)
    k_edge_gat<<<nb2, 256, 0, stream>>>(off, ssrc, H, att, hs, nullptr, (float*)hs, N, 1);

    // H (= d_out) now dead; materialize outputs as f32.
    hipMemcpyAsync((float*)d_out, (float*)hs, (size_t)N * 64 * 4, hipMemcpyDeviceToDevice, stream);
    k_cvt<<<(N * 64 + 255) / 256, 256, 0, stream>>>(hp, (float*)d_out + (size_t)N * 64, N * 64);

    // Diagnostic: if workspace too small, out[0] reads ~100000 + MB*1000.
    if (bad) {
        float v = 100000.f + 1000.f * (float)(ws_size >> 20);
        k_tracer<<<1, 64, 0, stream>>>((float*)d_out, v);
    }
}